// Round 9
// baseline (718.136 us; speedup 1.0000x reference)
//
#include <hip/hip_runtime.h>
#include <math.h>

#define F_IN 256
#define CH   16
#define NL   7

#define BS    64          // nodes per bucket (dL fits 6 bits)
#define CHE   16384       // edges per scatter chunk (runs of ~10.5 edges/bucket)
#define MAXNB 2048        // LDS cap for bucket arrays (NB=1563 actual)
#define NSEG  8           // segments for the column scan

// ---------------------------------------------------------------- chunk histogram: H[c][b] = #edges of chunk c with dst in bucket b
__global__ __launch_bounds__(1024) void k_hist(const int* __restrict__ dst, int E, int NB,
                                               int* __restrict__ H) {
    __shared__ int h[MAXNB];
    int c = blockIdx.x, tid = threadIdx.x;
    for (int i = tid; i < NB; i += 1024) h[i] = 0;
    __syncthreads();
    int beg = c * CHE, end = min(beg + CHE, E);
    for (int e = beg + tid; e < end; e += 1024) atomicAdd(&h[dst[e] >> 6], 1);
    __syncthreads();
    int* Hrow = H + (size_t)c * NB;
    for (int i = tid; i < NB; i += 1024) Hrow[i] = h[i];
}

// ---------------------------------------------------------------- segmented column sums: S[s][b] = sum_{c in seg s} H[c][b]
__global__ __launch_bounds__(256) void k_colsum8(const int* __restrict__ H, int NB, int C,
                                                 int seglen, int* __restrict__ S) {
    int b = blockIdx.x * 256 + threadIdx.x;
    int s = blockIdx.y;
    if (b >= NB) return;
    int c0 = s * seglen, c1 = min(c0 + seglen, C);
    int acc = 0;
    for (int c = c0; c < c1; ++c) acc += H[(size_t)c * NB + b];
    S[(size_t)s * NB + b] = acc;
}

// ---------------------------------------------------------------- exclusive scan of bucket totals (1 WG, 2/thread; sums S inline)
__global__ __launch_bounds__(1024) void k_scanbase(const int* __restrict__ S, int NB, int E,
                                                   int* __restrict__ base) {
    __shared__ int sm[1024];
    int t = threadIdx.x;
    int i0 = 2 * t, i1 = 2 * t + 1;
    int v0 = 0, v1 = 0;
    if (i0 < NB) {
#pragma unroll
        for (int s = 0; s < NSEG; ++s) v0 += S[(size_t)s * NB + i0];
    }
    if (i1 < NB) {
#pragma unroll
        for (int s = 0; s < NSEG; ++s) v1 += S[(size_t)s * NB + i1];
    }
    sm[t] = v0 + v1;
    __syncthreads();
    for (int off = 1; off < 1024; off <<= 1) {
        int u = (t >= off) ? sm[t - off] : 0;
        __syncthreads();
        sm[t] += u;
        __syncthreads();
    }
    int ex = sm[t] - (v0 + v1);
    if (i0 < NB) base[i0] = ex;
    if (i1 < NB) base[i1] = ex + v0;
    if (t == 0) base[NB] = E;
}

// ---------------------------------------------------------------- per-segment start: SB[s][b] = base[b] + sum_{s'<s} S[s'][b]
__global__ __launch_bounds__(256) void k_segoff(const int* __restrict__ S, const int* __restrict__ base,
                                                int NB, int* __restrict__ SB) {
    int b = blockIdx.x * 256 + threadIdx.x;
    if (b >= NB) return;
    int run = base[b];
#pragma unroll
    for (int s = 0; s < NSEG; ++s) {
        SB[(size_t)s * NB + b] = run;
        run += S[(size_t)s * NB + b];
    }
}

// ---------------------------------------------------------------- segmented column scan: H[c][b] <- absolute start offset
__global__ __launch_bounds__(256) void k_colscan8(int* __restrict__ H, const int* __restrict__ SB,
                                                  int NB, int C, int seglen) {
    int b = blockIdx.x * 256 + threadIdx.x;
    int s = blockIdx.y;
    if (b >= NB) return;
    int c0 = s * seglen, c1 = min(c0 + seglen, C);
    int run = SB[(size_t)s * NB + b];
    for (int c = c0; c < c1; ++c) {
        size_t idx = (size_t)c * NB + b;
        int t = H[idx];
        H[idx] = run;
        run += t;
    }
}

// ---------------------------------------------------------------- scatter: LDS cursor sort, DIRECT scattered store (20 KB LDS)
__global__ __launch_bounds__(1024) void k_scatter2(const int* __restrict__ src, const int* __restrict__ dst,
                                                   int E, int NB, const int* __restrict__ H,
                                                   int* __restrict__ packed) {
    __shared__ int lcur[MAXNB];            // exclusive starts, then running cursors
    __shared__ int ldel[MAXNB];            // global base - local start
    __shared__ int ssc[1024];
    int c = blockIdx.x, tid = threadIdx.x;
    int beg = c * CHE, end = min(beg + CHE, E);

    for (int i = tid; i < NB; i += 1024) lcur[i] = 0;
    __syncthreads();
    for (int e = beg + tid; e < end; e += 1024) atomicAdd(&lcur[dst[e] >> 6], 1);
    __syncthreads();

    // exclusive scan of lcur[0..NB), 2 elements per thread
    int i0 = 2 * tid;
    int a0 = (i0 < NB) ? lcur[i0] : 0;
    int a1 = (i0 + 1 < NB) ? lcur[i0 + 1] : 0;
    int tsum = a0 + a1;
    ssc[tid] = tsum;
    __syncthreads();
    for (int off = 1; off < 1024; off <<= 1) {
        int u = (tid >= off) ? ssc[tid - off] : 0;
        __syncthreads();
        ssc[tid] += u;
        __syncthreads();
    }
    int ex = ssc[tid] - tsum;
    if (i0 < NB) lcur[i0] = ex;
    if (i0 + 1 < NB) lcur[i0 + 1] = ex + a0;
    __syncthreads();

    const int* Hrow = H + (size_t)c * NB;
    for (int i = tid; i < NB; i += 1024) ldel[i] = Hrow[i] - lcur[i];
    __syncthreads();

    // place edges: LDS cursor gives unique slot; store directly (fire-and-forget)
    for (int e = beg + tid; e < end; e += 1024) {
        int d = dst[e], s = src[e];
        int bb = d >> 6;
        int p = atomicAdd(&lcur[bb], 1);
        packed[ldel[bb] + p] = s | ((d & (BS - 1)) << 17);
    }
}

// ---------------------------------------------------------------- dinv from bucketed edges
__global__ __launch_bounds__(256) void k_dinv(const int* __restrict__ packed, const int* __restrict__ base,
                                              int N, float* __restrict__ dinv) {
    __shared__ int cnt[BS];
    int b = blockIdx.x, tid = threadIdx.x;
    if (tid < BS) cnt[tid] = 0;
    __syncthreads();
    int beg = base[b], end = base[b + 1];
    for (int e = beg + tid; e < end; e += 256) atomicAdd(&cnt[(packed[e] >> 17) & (BS - 1)], 1);
    __syncthreads();
    int node = b * BS + tid;
    if (tid < BS && node < N) dinv[node] = rsqrtf((float)(cnt[tid] + 1));
}

// ---------------------------------------------------------------- gemm1: g = (x @ W0) * dinv
__global__ __launch_bounds__(256) void k_gemm1(const float* __restrict__ x,
                                               const float* __restrict__ W0,
                                               const float* __restrict__ dinv,
                                               float* __restrict__ g, int N) {
    int lane = threadIdx.x & 63;
    int q = lane >> 4;
    int c = lane & 15;
    float w[64];
#pragma unroll
    for (int t = 0; t < 64; ++t) w[t] = W0[(q * 64 + t) * CH + c];

    int wave  = (blockIdx.x * blockDim.x + threadIdx.x) >> 6;
    int nwave = (gridDim.x * blockDim.x) >> 6;
    for (int row = wave; row < N; row += nwave) {
        const float4* xp = (const float4*)(x + row * F_IN + q * 64);
        float acc = 0.f;
#pragma unroll
        for (int t = 0; t < 16; ++t) {
            float4 v = xp[t];
            acc += v.x * w[4*t] + v.y * w[4*t+1] + v.z * w[4*t+2] + v.w * w[4*t+3];
        }
        acc += __shfl_xor(acc, 16);
        acc += __shfl_xor(acc, 32);
        if (q == 0) g[row * CH + c] = acc * dinv[row];
    }
}

// ---------------------------------------------------------------- layer1 push: accA[dst] += g[src]  (aligned rows, 1 line-RMW/edge)
__global__ void k_edge1(const int* __restrict__ src, const int* __restrict__ dst,
                        const float* __restrict__ g, float* __restrict__ accA, int E) {
    long long tid = (long long)blockIdx.x * blockDim.x + threadIdx.x;
    int e = (int)(tid >> 4), c = (int)(tid & 15);
    if (e >= E) return;
    unsafeAtomicAdd(&accA[(size_t)dst[e] * CH + c], g[(size_t)src[e] * CH + c]);
}

// ---------------------------------------------------------------- layer2 transform: g2 = (relu(dinv*(accA+g)) @ W1) * dinv
__global__ __launch_bounds__(256) void k_layer2t(const float* __restrict__ g,
                                                 const float* __restrict__ accA,
                                                 const float* __restrict__ W1,
                                                 const float* __restrict__ dinv,
                                                 float* __restrict__ g2, int N) {
    int tid = blockIdx.x * 256 + threadIdx.x;
    int node = tid >> 4, c = tid & 15;
    if (node >= N) return;
    float dv = dinv[node];
    float h = fmaxf((accA[(size_t)node * CH + c] + g[(size_t)node * CH + c]) * dv, 0.f);
    float w1[NL];
#pragma unroll
    for (int j = 0; j < NL; ++j) w1[j] = W1[c * NL + j];
    float y = 0.f;
#pragma unroll
    for (int j = 0; j < NL; ++j) {
        float p = h * w1[j];
        p += __shfl_xor(p, 8, 16);
        p += __shfl_xor(p, 4, 16);
        p += __shfl_xor(p, 2, 16);
        p += __shfl_xor(p, 1, 16);
        if (c == j) y = p;
    }
    if (c < 8) g2[(size_t)node * 8 + c] = (c < NL) ? y * dv : 0.f;
}

// ---------------------------------------------------------------- agg2: pull from L2-resident g2 (16 gathers in flight) + exp
__global__ __launch_bounds__(1024) void k_agg2(const float* __restrict__ g2,
                                               const int* __restrict__ packed,
                                               const int* __restrict__ base,
                                               const float* __restrict__ dinv,
                                               float* __restrict__ out, int N) {
    __shared__ float acc[BS * 8];    // 2 KB
    int b = blockIdx.x, tid = threadIdx.x;
    int j = tid & 7, er = tid >> 3;
    for (int i = tid; i < BS * 8; i += 1024) acc[i] = 0.f;
    __syncthreads();

    int beg = base[b], end = base[b + 1];
    for (int eb = beg; eb < end; eb += 2048) {
        int v[16]; float xv[16]; bool pr[16];
#pragma unroll
        for (int k = 0; k < 16; ++k) {
            int e = eb + k * 128 + er;
            pr[k] = e < end;
            v[k] = pr[k] ? __builtin_nontemporal_load(packed + e) : 0;
        }
#pragma unroll
        for (int k = 0; k < 16; ++k)
            xv[k] = pr[k] ? g2[(v[k] & 0x1FFFF) * 8 + j] : 0.f;
#pragma unroll
        for (int k = 0; k < 16; ++k)
            if (pr[k]) atomicAdd(&acc[((v[k] >> 17) & (BS - 1)) * 8 + j], xv[k]);
    }
    __syncthreads();

    if (tid < BS * 8) {
        int nL = tid >> 3;
        int node = b * BS + nL;
        if (node < N && j < NL) {
            float dv = dinv[node];
            out[(size_t)node * NL + j] = __expf((acc[nL * 8 + j] + g2[node * 8 + j]) * dv) + 1.0f;
        }
    }
}

static inline size_t align64(size_t n) { return (n + 63) & ~(size_t)63; }  // 64 elems = 256 B

extern "C" void kernel_launch(void* const* d_in, const int* in_sizes, int n_in,
                              void* d_out, int out_size, void* d_ws, size_t ws_size,
                              hipStream_t stream) {
    const float* x  = (const float*)d_in[0];
    const float* W0 = (const float*)d_in[1];
    const float* W1 = (const float*)d_in[2];
    const int*   ei = (const int*)d_in[3];

    const int N = in_sizes[0] / F_IN;       // 100000
    const int E = in_sizes[3] / 2;          // 3200000
    const int* src = ei;
    const int* dst = ei + E;

    const int NB = (N + BS - 1) / BS;       // 1563
    const int C  = (E + CHE - 1) / CHE;     // 196
    const int SEGLEN = (C + NSEG - 1) / NSEG;  // 25
    const int NBG = (NB + 255) / 256;       // 7

    // workspace (all buffers 256B-aligned; ~29 MB):
    // H[C*NB] | S[8*NB] | SB[8*NB] | base[NB+1] | packed[E] | dinv[N] | g[N*16] | g2[N*8] | accA[N*16]
    size_t off = 0;
    int* H       = (int*)d_ws + off;           off += align64((size_t)C * NB);
    int* S       = (int*)d_ws + off;           off += align64((size_t)NSEG * NB);
    int* SB      = (int*)d_ws + off;           off += align64((size_t)NSEG * NB);
    int* base    = (int*)d_ws + off;           off += align64((size_t)NB + 1);
    int* packed  = (int*)d_ws + off;           off += align64((size_t)E);
    float* dinv  = (float*)d_ws + off;         off += align64((size_t)N);
    float* g     = (float*)d_ws + off;         off += align64((size_t)N * CH);
    float* g2    = (float*)d_ws + off;         off += align64((size_t)N * 8);
    float* accA  = (float*)d_ws + off;         off += align64((size_t)N * CH);

    float* out = (float*)d_out;

    // zero the layer-1 accumulator (6.4 MB)
    hipMemsetAsync(accA, 0, (size_t)N * CH * sizeof(float), stream);

    // 1) per-chunk bucket histograms
    k_hist<<<C, 1024, 0, stream>>>(dst, E, NB, H);

    // 2) bucket bases: segmented column scan (k_tot folded into k_scanbase)
    k_colsum8<<<dim3(NBG, NSEG), 256, 0, stream>>>(H, NB, C, SEGLEN, S);
    k_scanbase<<<1, 1024, 0, stream>>>(S, NB, E, base);
    k_segoff<<<NBG, 256, 0, stream>>>(S, base, NB, SB);
    k_colscan8<<<dim3(NBG, NSEG), 256, 0, stream>>>(H, SB, NB, C, SEGLEN);

    // 3) chunked counting-sort scatter (direct store, 20 KB LDS)
    k_scatter2<<<C, 1024, 0, stream>>>(src, dst, E, NB, H, packed);

    // 4) dinv from bucketed edges (no global atomics)
    k_dinv<<<NB, 256, 0, stream>>>(packed, base, N, dinv);

    // 5) g = (x@W0) * dinv   [N][16], 64B-aligned rows
    k_gemm1<<<2048, 256, 0, stream>>>(x, W0, dinv, g, N);

    // 6) layer1 via flat atomic PUSH (1 line-fetch + 1 line-RMW per edge)
    {
        long long tot = (long long)E * CH;
        k_edge1<<<(int)((tot + 255) / 256), 256, 0, stream>>>(src, dst, g, accA, E);
    }

    // 7) layer2 transform: relu + W1 + dinv -> g2[N][8]
    k_layer2t<<<(N * 16 + 255) / 256, 256, 0, stream>>>(g, accA, W1, dinv, g2, N);

    // 8) layer2 aggregate via pull (16-deep MLP) + fused exp epilogue
    k_agg2<<<NB, 1024, 0, stream>>>(g2, packed, base, dinv, out, N);
}

// Round 10
// 682.193 us; speedup vs baseline: 1.0527x; 1.0527x over previous
//
#include <hip/hip_runtime.h>
#include <math.h>

#define F_IN 256
#define CH   16
#define NL   7

#define BS    64          // nodes per bucket (dL fits 6 bits)
#define CHE   8192        // edges per scatter chunk
#define MAXNB 2048        // LDS cap for bucket arrays (NB=1563 actual)
#define NSEG  8           // segments for the column scan

// ---------------------------------------------------------------- chunk histogram: H[c][b] = #edges of chunk c with dst in bucket b
__global__ __launch_bounds__(1024) void k_hist(const int* __restrict__ dst, int E, int NB,
                                               int* __restrict__ H) {
    __shared__ int h[MAXNB];
    int c = blockIdx.x, tid = threadIdx.x;
    for (int i = tid; i < NB; i += 1024) h[i] = 0;
    __syncthreads();
    int beg = c * CHE, end = min(beg + CHE, E);
    for (int e = beg + tid; e < end; e += 1024) atomicAdd(&h[dst[e] >> 6], 1);
    __syncthreads();
    int* Hrow = H + (size_t)c * NB;
    for (int i = tid; i < NB; i += 1024) Hrow[i] = h[i];
}

// ---------------------------------------------------------------- segmented column sums: S[s][b] = sum_{c in seg s} H[c][b]
__global__ __launch_bounds__(256) void k_colsum8(const int* __restrict__ H, int NB, int C,
                                                 int seglen, int* __restrict__ S) {
    int b = blockIdx.x * 256 + threadIdx.x;
    int s = blockIdx.y;
    if (b >= NB) return;
    int c0 = s * seglen, c1 = min(c0 + seglen, C);
    int acc = 0;
    for (int c = c0; c < c1; ++c) acc += H[(size_t)c * NB + b];
    S[(size_t)s * NB + b] = acc;
}

// ---------------------------------------------------------------- exclusive scan of bucket totals (1 WG, 2/thread; sums S inline)
__global__ __launch_bounds__(1024) void k_scanbase(const int* __restrict__ S, int NB, int E,
                                                   int* __restrict__ base) {
    __shared__ int sm[1024];
    int t = threadIdx.x;
    int i0 = 2 * t, i1 = 2 * t + 1;
    int v0 = 0, v1 = 0;
    if (i0 < NB) {
#pragma unroll
        for (int s = 0; s < NSEG; ++s) v0 += S[(size_t)s * NB + i0];
    }
    if (i1 < NB) {
#pragma unroll
        for (int s = 0; s < NSEG; ++s) v1 += S[(size_t)s * NB + i1];
    }
    sm[t] = v0 + v1;
    __syncthreads();
    for (int off = 1; off < 1024; off <<= 1) {
        int u = (t >= off) ? sm[t - off] : 0;
        __syncthreads();
        sm[t] += u;
        __syncthreads();
    }
    int ex = sm[t] - (v0 + v1);
    if (i0 < NB) base[i0] = ex;
    if (i1 < NB) base[i1] = ex + v0;
    if (t == 0) base[NB] = E;
}

// ---------------------------------------------------------------- per-segment start: SB[s][b] = base[b] + sum_{s'<s} S[s'][b]
__global__ __launch_bounds__(256) void k_segoff(const int* __restrict__ S, const int* __restrict__ base,
                                                int NB, int* __restrict__ SB) {
    int b = blockIdx.x * 256 + threadIdx.x;
    if (b >= NB) return;
    int run = base[b];
#pragma unroll
    for (int s = 0; s < NSEG; ++s) {
        SB[(size_t)s * NB + b] = run;
        run += S[(size_t)s * NB + b];
    }
}

// ---------------------------------------------------------------- segmented column scan: H[c][b] <- absolute start offset
__global__ __launch_bounds__(256) void k_colscan8(int* __restrict__ H, const int* __restrict__ SB,
                                                  int NB, int C, int seglen) {
    int b = blockIdx.x * 256 + threadIdx.x;
    int s = blockIdx.y;
    if (b >= NB) return;
    int c0 = s * seglen, c1 = min(c0 + seglen, C);
    int run = SB[(size_t)s * NB + b];
    for (int c = c0; c < c1; ++c) {
        size_t idx = (size_t)c * NB + b;
        int t = H[idx];
        H[idx] = run;
        run += t;
    }
}

// ---------------------------------------------------------------- scatter: LDS-local counting sort per chunk, linear writeout (R8 form)
__global__ __launch_bounds__(1024) void k_scatter2(const int* __restrict__ src, const int* __restrict__ dst,
                                                   int E, int NB, const int* __restrict__ H,
                                                   int* __restrict__ packed) {
    __shared__ int lcur[MAXNB];            // exclusive starts, then running cursors
    __shared__ int ldel[MAXNB];            // global base - local start
    __shared__ int ssc[1024];
    __shared__ int lval[CHE];
    __shared__ unsigned short lbkt[CHE];   // bucket id per local slot
    int c = blockIdx.x, tid = threadIdx.x;
    int beg = c * CHE, end = min(beg + CHE, E), n = end - beg;

    for (int i = tid; i < NB; i += 1024) lcur[i] = 0;
    __syncthreads();
    for (int e = beg + tid; e < end; e += 1024) atomicAdd(&lcur[dst[e] >> 6], 1);
    __syncthreads();

    // exclusive scan of lcur[0..NB), 2 elements per thread
    int i0 = 2 * tid;
    int a0 = (i0 < NB) ? lcur[i0] : 0;
    int a1 = (i0 + 1 < NB) ? lcur[i0 + 1] : 0;
    int tsum = a0 + a1;
    ssc[tid] = tsum;
    __syncthreads();
    for (int off = 1; off < 1024; off <<= 1) {
        int u = (tid >= off) ? ssc[tid - off] : 0;
        __syncthreads();
        ssc[tid] += u;
        __syncthreads();
    }
    int ex = ssc[tid] - tsum;
    if (i0 < NB) lcur[i0] = ex;
    if (i0 + 1 < NB) lcur[i0 + 1] = ex + a0;
    __syncthreads();

    const int* Hrow = H + (size_t)c * NB;
    for (int i = tid; i < NB; i += 1024) ldel[i] = Hrow[i] - lcur[i];
    __syncthreads();

    // place edges into LDS in bucket-sorted local order
    for (int e = beg + tid; e < end; e += 1024) {
        int d = dst[e], s = src[e];
        int bb = d >> 6;
        int p = atomicAdd(&lcur[bb], 1);
        lval[p] = s | ((d & (BS - 1)) << 17);
        lbkt[p] = (unsigned short)bb;
    }
    __syncthreads();

    // linear writeout (coalesced within bucket runs)
    for (int p = tid; p < n; p += 1024)
        packed[ldel[lbkt[p]] + p] = lval[p];
}

// ---------------------------------------------------------------- dinv from bucketed edges
__global__ __launch_bounds__(256) void k_dinv(const int* __restrict__ packed, const int* __restrict__ base,
                                              int N, float* __restrict__ dinv) {
    __shared__ int cnt[BS];
    int b = blockIdx.x, tid = threadIdx.x;
    if (tid < BS) cnt[tid] = 0;
    __syncthreads();
    int beg = base[b], end = base[b + 1];
    for (int e = beg + tid; e < end; e += 256) atomicAdd(&cnt[(packed[e] >> 17) & (BS - 1)], 1);
    __syncthreads();
    int node = b * BS + tid;
    if (tid < BS && node < N) dinv[node] = rsqrtf((float)(cnt[tid] + 1));
}

// ---------------------------------------------------------------- gemm1: g = (x @ W0) * dinv
__global__ __launch_bounds__(256) void k_gemm1(const float* __restrict__ x,
                                               const float* __restrict__ W0,
                                               const float* __restrict__ dinv,
                                               float* __restrict__ g, int N) {
    int lane = threadIdx.x & 63;
    int q = lane >> 4;
    int c = lane & 15;
    float w[64];
#pragma unroll
    for (int t = 0; t < 64; ++t) w[t] = W0[(q * 64 + t) * CH + c];

    int wave  = (blockIdx.x * blockDim.x + threadIdx.x) >> 6;
    int nwave = (gridDim.x * blockDim.x) >> 6;
    for (int row = wave; row < N; row += nwave) {
        const float4* xp = (const float4*)(x + row * F_IN + q * 64);
        float acc = 0.f;
#pragma unroll
        for (int t = 0; t < 16; ++t) {
            float4 v = xp[t];
            acc += v.x * w[4*t] + v.y * w[4*t+1] + v.z * w[4*t+2] + v.w * w[4*t+3];
        }
        acc += __shfl_xor(acc, 16);
        acc += __shfl_xor(acc, 32);
        if (q == 0) g[row * CH + c] = acc * dinv[row];
    }
}

// ---------------------------------------------------------------- layer1 push: accA[dst] += g[src]  (aligned rows, 1 line-RMW/edge)
__global__ void k_edge1(const int* __restrict__ src, const int* __restrict__ dst,
                        const float* __restrict__ g, float* __restrict__ accA, int E) {
    long long tid = (long long)blockIdx.x * blockDim.x + threadIdx.x;
    int e = (int)(tid >> 4), c = (int)(tid & 15);
    if (e >= E) return;
    unsafeAtomicAdd(&accA[(size_t)dst[e] * CH + c], g[(size_t)src[e] * CH + c]);
}

// ---------------------------------------------------------------- layer2 transform: g2 = (relu(dinv*(accA+g)) @ W1) * dinv
__global__ __launch_bounds__(256) void k_layer2t(const float* __restrict__ g,
                                                 const float* __restrict__ accA,
                                                 const float* __restrict__ W1,
                                                 const float* __restrict__ dinv,
                                                 float* __restrict__ g2, int N) {
    int tid = blockIdx.x * 256 + threadIdx.x;
    int node = tid >> 4, c = tid & 15;
    if (node >= N) return;
    float dv = dinv[node];
    float h = fmaxf((accA[(size_t)node * CH + c] + g[(size_t)node * CH + c]) * dv, 0.f);
    float w1[NL];
#pragma unroll
    for (int j = 0; j < NL; ++j) w1[j] = W1[c * NL + j];
    float y = 0.f;
#pragma unroll
    for (int j = 0; j < NL; ++j) {
        float p = h * w1[j];
        p += __shfl_xor(p, 8, 16);
        p += __shfl_xor(p, 4, 16);
        p += __shfl_xor(p, 2, 16);
        p += __shfl_xor(p, 1, 16);
        if (c == j) y = p;
    }
    if (c < 8) g2[(size_t)node * 8 + c] = (c < NL) ? y * dv : 0.f;
}

// ---------------------------------------------------------------- agg2: pull from L2-resident g2; CONSECUTIVE edges per group +
//      register run-accumulation (sorted dst) -> ~1-2 LDS atomics per 16-edge span
__global__ __launch_bounds__(1024) void k_agg2(const float* __restrict__ g2,
                                               const int* __restrict__ packed,
                                               const int* __restrict__ base,
                                               const float* __restrict__ dinv,
                                               float* __restrict__ out, int N) {
    __shared__ float acc[BS * 8];    // 2 KB
    int b = blockIdx.x, tid = threadIdx.x;
    int j = tid & 7, er = tid >> 3;  // er 0..127, each group owns 16 consecutive edges
    for (int i = tid; i < BS * 8; i += 1024) acc[i] = 0.f;
    __syncthreads();

    int beg = base[b], end = base[b + 1];
    for (int eb = beg; eb < end; eb += 2048) {
        int e0 = eb + er * 16;
        int v[16]; float xv[16]; bool pr[16];
#pragma unroll
        for (int k = 0; k < 16; ++k) {
            int e = e0 + k;
            pr[k] = e < end;
            v[k] = pr[k] ? __builtin_nontemporal_load(packed + e) : 0;
        }
#pragma unroll
        for (int k = 0; k < 16; ++k)
            xv[k] = pr[k] ? g2[(v[k] & 0x1FFFF) * 8 + j] : 0.f;

        // register segmented reduction over the sorted run
        float racc = 0.f; int cur = -1;
#pragma unroll
        for (int k = 0; k < 16; ++k) {
            if (pr[k]) {
                int dL = (v[k] >> 17) & (BS - 1);
                if (dL != cur) {
                    if (cur >= 0) atomicAdd(&acc[cur * 8 + j], racc);
                    cur = dL; racc = 0.f;
                }
                racc += xv[k];
            }
        }
        if (cur >= 0) atomicAdd(&acc[cur * 8 + j], racc);
    }
    __syncthreads();

    if (tid < BS * 8) {
        int nL = tid >> 3;
        int node = b * BS + nL;
        if (node < N && j < NL) {
            float dv = dinv[node];
            out[(size_t)node * NL + j] = __expf((acc[nL * 8 + j] + g2[node * 8 + j]) * dv) + 1.0f;
        }
    }
}

static inline size_t align64(size_t n) { return (n + 63) & ~(size_t)63; }  // 64 elems = 256 B

extern "C" void kernel_launch(void* const* d_in, const int* in_sizes, int n_in,
                              void* d_out, int out_size, void* d_ws, size_t ws_size,
                              hipStream_t stream) {
    const float* x  = (const float*)d_in[0];
    const float* W0 = (const float*)d_in[1];
    const float* W1 = (const float*)d_in[2];
    const int*   ei = (const int*)d_in[3];

    const int N = in_sizes[0] / F_IN;       // 100000
    const int E = in_sizes[3] / 2;          // 3200000
    const int* src = ei;
    const int* dst = ei + E;

    const int NB = (N + BS - 1) / BS;       // 1563
    const int C  = (E + CHE - 1) / CHE;     // 391
    const int SEGLEN = (C + NSEG - 1) / NSEG;  // 49
    const int NBG = (NB + 255) / 256;       // 7

    // workspace (all buffers 256B-aligned; ~31.8 MB):
    // H[C*NB] | S[8*NB] | SB[8*NB] | base[NB+1] | packed[E] | dinv[N] | g[N*16] | g2[N*8] | accA[N*16]
    size_t off = 0;
    int* H       = (int*)d_ws + off;           off += align64((size_t)C * NB);
    int* S       = (int*)d_ws + off;           off += align64((size_t)NSEG * NB);
    int* SB      = (int*)d_ws + off;           off += align64((size_t)NSEG * NB);
    int* base    = (int*)d_ws + off;           off += align64((size_t)NB + 1);
    int* packed  = (int*)d_ws + off;           off += align64((size_t)E);
    float* dinv  = (float*)d_ws + off;         off += align64((size_t)N);
    float* g     = (float*)d_ws + off;         off += align64((size_t)N * CH);
    float* g2    = (float*)d_ws + off;         off += align64((size_t)N * 8);
    float* accA  = (float*)d_ws + off;         off += align64((size_t)N * CH);

    float* out = (float*)d_out;

    // zero the layer-1 accumulator (6.4 MB)
    hipMemsetAsync(accA, 0, (size_t)N * CH * sizeof(float), stream);

    // 1) per-chunk bucket histograms
    k_hist<<<C, 1024, 0, stream>>>(dst, E, NB, H);

    // 2) bucket bases: segmented column scan
    k_colsum8<<<dim3(NBG, NSEG), 256, 0, stream>>>(H, NB, C, SEGLEN, S);
    k_scanbase<<<1, 1024, 0, stream>>>(S, NB, E, base);
    k_segoff<<<NBG, 256, 0, stream>>>(S, base, NB, SB);
    k_colscan8<<<dim3(NBG, NSEG), 256, 0, stream>>>(H, SB, NB, C, SEGLEN);

    // 3) chunked counting-sort scatter (R8 LDS-staged linear writeout)
    k_scatter2<<<C, 1024, 0, stream>>>(src, dst, E, NB, H, packed);

    // 4) dinv from bucketed edges (no global atomics)
    k_dinv<<<NB, 256, 0, stream>>>(packed, base, N, dinv);

    // 5) g = (x@W0) * dinv   [N][16], 64B-aligned rows
    k_gemm1<<<2048, 256, 0, stream>>>(x, W0, dinv, g, N);

    // 6) layer1 via flat atomic PUSH (1 line-fetch + 1 line-RMW per edge)
    {
        long long tot = (long long)E * CH;
        k_edge1<<<(int)((tot + 255) / 256), 256, 0, stream>>>(src, dst, g, accA, E);
    }

    // 7) layer2 transform: relu + W1 + dinv -> g2[N][8]
    k_layer2t<<<(N * 16 + 255) / 256, 256, 0, stream>>>(g, accA, W1, dinv, g2, N);

    // 8) layer2 aggregate via pull (register run-accumulation) + fused exp epilogue
    k_agg2<<<NB, 1024, 0, stream>>>(g2, packed, base, dinv, out, N);
}

// Round 12
// 407.031 us; speedup vs baseline: 1.7643x; 1.6760x over previous
//
#include <hip/hip_runtime.h>
#include <math.h>

#define F_IN 256
#define CH   16
#define NL   7

#define BS    128         // nodes per bucket (dL fits 7 bits, pack at bit 17)
#define CHE   8192        // edges per scatter chunk
#define MAXNB 1024        // LDS cap for bucket arrays (NB=782 actual)
#define NSEG  8           // segments for the column scan
#define ECAP  5120        // LDS edge-stage capacity per bucket (mean 4096, sd 64)

// ---------------------------------------------------------------- chunk histogram: H[c][b] = #edges of chunk c with dst in bucket b
__global__ __launch_bounds__(1024) void k_hist(const int* __restrict__ dst, int E, int NB,
                                               int* __restrict__ H) {
    __shared__ int h[MAXNB];
    int c = blockIdx.x, tid = threadIdx.x;
    for (int i = tid; i < NB; i += 1024) h[i] = 0;
    __syncthreads();
    int beg = c * CHE, end = min(beg + CHE, E);
    for (int e = beg + tid; e < end; e += 1024) atomicAdd(&h[dst[e] >> 7], 1);
    __syncthreads();
    int* Hrow = H + (size_t)c * NB;
    for (int i = tid; i < NB; i += 1024) Hrow[i] = h[i];
}

// ---------------------------------------------------------------- segmented column sums: S[s][b] = sum_{c in seg s} H[c][b]
__global__ __launch_bounds__(256) void k_colsum8(const int* __restrict__ H, int NB, int C,
                                                 int seglen, int* __restrict__ S) {
    int b = blockIdx.x * 256 + threadIdx.x;
    int s = blockIdx.y;
    if (b >= NB) return;
    int c0 = s * seglen, c1 = min(c0 + seglen, C);
    int acc = 0;
    for (int c = c0; c < c1; ++c) acc += H[(size_t)c * NB + b];
    S[(size_t)s * NB + b] = acc;
}

// ---------------------------------------------------------------- exclusive scan of bucket totals (1 WG, 2/thread; sums S inline)
__global__ __launch_bounds__(1024) void k_scanbase(const int* __restrict__ S, int NB, int E,
                                                   int* __restrict__ base) {
    __shared__ int sm[1024];
    int t = threadIdx.x;
    int i0 = 2 * t, i1 = 2 * t + 1;
    int v0 = 0, v1 = 0;
    if (i0 < NB) {
#pragma unroll
        for (int s = 0; s < NSEG; ++s) v0 += S[(size_t)s * NB + i0];
    }
    if (i1 < NB) {
#pragma unroll
        for (int s = 0; s < NSEG; ++s) v1 += S[(size_t)s * NB + i1];
    }
    sm[t] = v0 + v1;
    __syncthreads();
    for (int off = 1; off < 1024; off <<= 1) {
        int u = (t >= off) ? sm[t - off] : 0;
        __syncthreads();
        sm[t] += u;
        __syncthreads();
    }
    int ex = sm[t] - (v0 + v1);
    if (i0 < NB) base[i0] = ex;
    if (i1 < NB) base[i1] = ex + v0;
    if (t == 0) base[NB] = E;
}

// ---------------------------------------------------------------- per-segment start: SB[s][b] = base[b] + sum_{s'<s} S[s'][b]
__global__ __launch_bounds__(256) void k_segoff(const int* __restrict__ S, const int* __restrict__ base,
                                                int NB, int* __restrict__ SB) {
    int b = blockIdx.x * 256 + threadIdx.x;
    if (b >= NB) return;
    int run = base[b];
#pragma unroll
    for (int s = 0; s < NSEG; ++s) {
        SB[(size_t)s * NB + b] = run;
        run += S[(size_t)s * NB + b];
    }
}

// ---------------------------------------------------------------- segmented column scan: H[c][b] <- absolute start offset
__global__ __launch_bounds__(256) void k_colscan8(int* __restrict__ H, const int* __restrict__ SB,
                                                  int NB, int C, int seglen) {
    int b = blockIdx.x * 256 + threadIdx.x;
    int s = blockIdx.y;
    if (b >= NB) return;
    int c0 = s * seglen, c1 = min(c0 + seglen, C);
    int run = SB[(size_t)s * NB + b];
    for (int c = c0; c < c1; ++c) {
        size_t idx = (size_t)c * NB + b;
        int t = H[idx];
        H[idx] = run;
        run += t;
    }
}

// ---------------------------------------------------------------- scatter: LDS-local counting sort per chunk, linear writeout
__global__ __launch_bounds__(1024) void k_scatter2(const int* __restrict__ src, const int* __restrict__ dst,
                                                   int E, int NB, const int* __restrict__ H,
                                                   int* __restrict__ packed) {
    __shared__ int lcur[MAXNB];            // exclusive starts, then running cursors
    __shared__ int ldel[MAXNB];            // global base - local start
    __shared__ int ssc[1024];
    __shared__ int lval[CHE];
    __shared__ unsigned short lbkt[CHE];   // bucket id per local slot
    int c = blockIdx.x, tid = threadIdx.x;
    int beg = c * CHE, end = min(beg + CHE, E), n = end - beg;

    for (int i = tid; i < NB; i += 1024) lcur[i] = 0;
    __syncthreads();
    for (int e = beg + tid; e < end; e += 1024) atomicAdd(&lcur[dst[e] >> 7], 1);
    __syncthreads();

    // exclusive scan of lcur[0..NB), 2 elements per thread
    int i0 = 2 * tid;
    int a0 = (i0 < NB) ? lcur[i0] : 0;
    int a1 = (i0 + 1 < NB) ? lcur[i0 + 1] : 0;
    int tsum = a0 + a1;
    ssc[tid] = tsum;
    __syncthreads();
    for (int off = 1; off < 1024; off <<= 1) {
        int u = (tid >= off) ? ssc[tid - off] : 0;
        __syncthreads();
        ssc[tid] += u;
        __syncthreads();
    }
    int ex = ssc[tid] - tsum;
    if (i0 < NB) lcur[i0] = ex;
    if (i0 + 1 < NB) lcur[i0 + 1] = ex + a0;
    __syncthreads();

    const int* Hrow = H + (size_t)c * NB;
    for (int i = tid; i < NB; i += 1024) ldel[i] = Hrow[i] - lcur[i];
    __syncthreads();

    // place edges into LDS in bucket-sorted local order
    for (int e = beg + tid; e < end; e += 1024) {
        int d = dst[e], s = src[e];
        int bb = d >> 7;
        int p = atomicAdd(&lcur[bb], 1);
        lval[p] = s | ((d & (BS - 1)) << 17);
        lbkt[p] = (unsigned short)bb;
    }
    __syncthreads();

    // linear writeout (coalesced within bucket runs)
    for (int p = tid; p < n; p += 1024)
        packed[ldel[lbkt[p]] + p] = lval[p];
}

// ---------------------------------------------------------------- nodesort: in-place sort of each bucket by node; emits rowptr + dinv
__global__ __launch_bounds__(256) void k_nodesort(int* __restrict__ packed,
                                                  const int* __restrict__ base,
                                                  int N,
                                                  int* __restrict__ rowptr,
                                                  float* __restrict__ dinv) {
    __shared__ int ebuf[ECAP];
    __shared__ int cnt[BS], cur[BS];
    int b = blockIdx.x, tid = threadIdx.x;
    int beg = base[b], end = base[b + 1];
    int m = end - beg;
    int mc = min(m, ECAP);
    for (int i = tid; i < mc; i += 256) ebuf[i] = packed[beg + i];
    int vov = -1;                         // overflow edge (read BEFORE any in-place writes)
    int i2 = ECAP + tid;
    if (i2 < m) vov = packed[beg + i2];
    if (tid < BS) cnt[tid] = 0;
    __syncthreads();
    for (int i = tid; i < mc; i += 256) atomicAdd(&cnt[(ebuf[i] >> 17) & (BS - 1)], 1);
    if (vov >= 0) atomicAdd(&cnt[(vov >> 17) & (BS - 1)], 1);
    __syncthreads();
    int v = (tid < BS) ? cnt[tid] : 0;
    for (int off = 1; off < BS; off <<= 1) {
        int u = (tid < BS && tid >= off) ? cnt[tid - off] : 0;
        __syncthreads();
        if (tid < BS) cnt[tid] += u;
        __syncthreads();
    }
    if (tid < BS) {
        int ex = cnt[tid] - v;           // exclusive start
        cur[tid] = ex;
        int node = b * BS + tid;
        if (node < N) dinv[node] = rsqrtf((float)(v + 1));
        if (node <= N) rowptr[node] = beg + ex;
    }
    __syncthreads();
    for (int i = tid; i < mc; i += 256) {
        int vv = ebuf[i];
        int p = atomicAdd(&cur[(vv >> 17) & (BS - 1)], 1);
        packed[beg + p] = vv;
    }
    if (vov >= 0) {
        int p = atomicAdd(&cur[(vov >> 17) & (BS - 1)], 1);
        packed[beg + p] = vov;
    }
}

// ---------------------------------------------------------------- gemm1: g = (x @ W0) * dinv
__global__ __launch_bounds__(256) void k_gemm1(const float* __restrict__ x,
                                               const float* __restrict__ W0,
                                               const float* __restrict__ dinv,
                                               float* __restrict__ g, int N) {
    int lane = threadIdx.x & 63;
    int q = lane >> 4;
    int c = lane & 15;
    float w[64];
#pragma unroll
    for (int t = 0; t < 64; ++t) w[t] = W0[(q * 64 + t) * CH + c];

    int wave  = (blockIdx.x * blockDim.x + threadIdx.x) >> 6;
    int nwave = (gridDim.x * blockDim.x) >> 6;
    for (int row = wave; row < N; row += nwave) {
        const float4* xp = (const float4*)(x + row * F_IN + q * 64);
        float acc = 0.f;
#pragma unroll
        for (int t = 0; t < 16; ++t) {
            float4 v = xp[t];
            acc += v.x * w[4*t] + v.y * w[4*t+1] + v.z * w[4*t+2] + v.w * w[4*t+3];
        }
        acc += __shfl_xor(acc, 16);
        acc += __shfl_xor(acc, 32);
        if (q == 0) g[row * CH + c] = acc * dinv[row];
    }
}

// ---------------------------------------------------------------- agg1n: layer1 CSR pull, REGISTER accumulation, fused relu+W1+dinv
// 2 threads per node (h = channel-half); zero atomics
__global__ __launch_bounds__(256) void k_agg1n(const float* __restrict__ g,
                                               const int* __restrict__ packed,
                                               const int* __restrict__ base,
                                               const int* __restrict__ rowptr,
                                               const float* __restrict__ W1,
                                               float* __restrict__ g2, int N) {
    __shared__ int ebuf[ECAP];
    __shared__ float hbuf[BS * 16];      // 8 KB
    __shared__ float w1s[16 * 8];        // W1 padded to stride 8
    int b = blockIdx.x, tid = threadIdx.x;
    int beg = base[b], end = base[b + 1], m = end - beg;
    int mc = min(m, ECAP);
    for (int i = tid; i < mc; i += 256) ebuf[i] = packed[beg + i];
    if (tid < 128) { int c = tid >> 3, j = tid & 7; w1s[tid] = (j < NL) ? W1[c * NL + j] : 0.f; }
    __syncthreads();

    int nL = tid >> 1, h = tid & 1;
    int n = b * BS + nL;
    float dv = 0.f;
    if (n < N) {
        int r0 = rowptr[n] - beg, r1 = rowptr[n + 1] - beg;
        dv = rsqrtf((float)(r1 - r0 + 1));
        const float4* gp = (const float4*)(g + (size_t)n * 16);
        float4 aL = gp[2 * h], aH = gp[2 * h + 1];   // self term
        int eEnd = min(r1, mc);
        int e = r0;
        for (; e + 4 <= eEnd; e += 4) {
            int s0 = ebuf[e] & 0x1FFFF, s1 = ebuf[e+1] & 0x1FFFF;
            int s2 = ebuf[e+2] & 0x1FFFF, s3 = ebuf[e+3] & 0x1FFFF;
            const float4* p0 = (const float4*)(g + (size_t)s0 * 16);
            const float4* p1 = (const float4*)(g + (size_t)s1 * 16);
            const float4* p2 = (const float4*)(g + (size_t)s2 * 16);
            const float4* p3 = (const float4*)(g + (size_t)s3 * 16);
            float4 l0 = p0[2*h], h0 = p0[2*h+1], l1 = p1[2*h], h1 = p1[2*h+1];
            float4 l2 = p2[2*h], h2 = p2[2*h+1], l3 = p3[2*h], h3 = p3[2*h+1];
            aL.x += l0.x + l1.x + l2.x + l3.x; aL.y += l0.y + l1.y + l2.y + l3.y;
            aL.z += l0.z + l1.z + l2.z + l3.z; aL.w += l0.w + l1.w + l2.w + l3.w;
            aH.x += h0.x + h1.x + h2.x + h3.x; aH.y += h0.y + h1.y + h2.y + h3.y;
            aH.z += h0.z + h1.z + h2.z + h3.z; aH.w += h0.w + h1.w + h2.w + h3.w;
        }
        for (; e < eEnd; ++e) {
            int s = ebuf[e] & 0x1FFFF;
            const float4* p = (const float4*)(g + (size_t)s * 16);
            float4 l = p[2*h], hh = p[2*h+1];
            aL.x += l.x; aL.y += l.y; aL.z += l.z; aL.w += l.w;
            aH.x += hh.x; aH.y += hh.y; aH.z += hh.z; aH.w += hh.w;
        }
        for (int e2 = max(r0, mc); e2 < r1; ++e2) {        // rare overflow tail
            int s = packed[beg + e2] & 0x1FFFF;
            const float4* p = (const float4*)(g + (size_t)s * 16);
            float4 l = p[2*h], hh = p[2*h+1];
            aL.x += l.x; aL.y += l.y; aL.z += l.z; aL.w += l.w;
            aH.x += hh.x; aH.y += hh.y; aH.z += hh.z; aH.w += hh.w;
        }
        float* hb = hbuf + nL * 16 + 8 * h;
        hb[0] = fmaxf(aL.x * dv, 0.f); hb[1] = fmaxf(aL.y * dv, 0.f);
        hb[2] = fmaxf(aL.z * dv, 0.f); hb[3] = fmaxf(aL.w * dv, 0.f);
        hb[4] = fmaxf(aH.x * dv, 0.f); hb[5] = fmaxf(aH.y * dv, 0.f);
        hb[6] = fmaxf(aH.z * dv, 0.f); hb[7] = fmaxf(aH.w * dv, 0.f);
    }
    __syncthreads();
    if (n < N) {
        int j0 = 4 * h;
        float y0 = 0.f, y1 = 0.f, y2 = 0.f, y3 = 0.f;
#pragma unroll
        for (int c = 0; c < 16; ++c) {
            float hc = hbuf[nL * 16 + c];
            y0 += hc * w1s[c * 8 + j0 + 0];
            y1 += hc * w1s[c * 8 + j0 + 1];
            y2 += hc * w1s[c * 8 + j0 + 2];
            y3 += hc * w1s[c * 8 + j0 + 3];   // j=7 column is zero-padded
        }
        float4 o; o.x = y0 * dv; o.y = y1 * dv; o.z = y2 * dv; o.w = y3 * dv;
        ((float4*)(g2 + (size_t)n * 8))[h] = o;
    }
}

// ---------------------------------------------------------------- agg2n: layer2 CSR pull, REGISTER accumulation, fused exp epilogue
__global__ __launch_bounds__(256) void k_agg2n(const float* __restrict__ g2,
                                               const int* __restrict__ packed,
                                               const int* __restrict__ base,
                                               const int* __restrict__ rowptr,
                                               float* __restrict__ out, int N) {
    __shared__ int ebuf[ECAP];
    int b = blockIdx.x, tid = threadIdx.x;
    int beg = base[b], end = base[b + 1], m = end - beg;
    int mc = min(m, ECAP);
    for (int i = tid; i < mc; i += 256) ebuf[i] = packed[beg + i];
    __syncthreads();

    int nL = tid >> 1, h = tid & 1;
    int n = b * BS + nL;
    if (n >= N) return;
    int r0 = rowptr[n] - beg, r1 = rowptr[n + 1] - beg;
    float dv = rsqrtf((float)(r1 - r0 + 1));
    float4 acc = ((const float4*)(g2 + (size_t)n * 8))[h];  // self term
    int eEnd = min(r1, mc);
    int e = r0;
    for (; e + 8 <= eEnd; e += 8) {
        int s[8];
#pragma unroll
        for (int k = 0; k < 8; ++k) s[k] = ebuf[e + k] & 0x1FFFF;
        float4 a[8];
#pragma unroll
        for (int k = 0; k < 8; ++k) a[k] = ((const float4*)(g2 + (size_t)s[k] * 8))[h];
#pragma unroll
        for (int k = 0; k < 8; ++k) {
            acc.x += a[k].x; acc.y += a[k].y; acc.z += a[k].z; acc.w += a[k].w;
        }
    }
    for (; e < eEnd; ++e) {
        int s = ebuf[e] & 0x1FFFF;
        float4 a = ((const float4*)(g2 + (size_t)s * 8))[h];
        acc.x += a.x; acc.y += a.y; acc.z += a.z; acc.w += a.w;
    }
    for (int e2 = max(r0, mc); e2 < r1; ++e2) {             // rare overflow tail
        int s = packed[beg + e2] & 0x1FFFF;
        float4 a = ((const float4*)(g2 + (size_t)s * 8))[h];
        acc.x += a.x; acc.y += a.y; acc.z += a.z; acc.w += a.w;
    }
    int j0 = 4 * h;
    float vals[4] = {acc.x, acc.y, acc.z, acc.w};
#pragma unroll
    for (int k = 0; k < 4; ++k)
        if (j0 + k < NL)
            out[(size_t)n * NL + j0 + k] = __expf(dv * vals[k]) + 1.0f;
}

static inline size_t align64(size_t n) { return (n + 63) & ~(size_t)63; }  // 64 elems = 256 B

extern "C" void kernel_launch(void* const* d_in, const int* in_sizes, int n_in,
                              void* d_out, int out_size, void* d_ws, size_t ws_size,
                              hipStream_t stream) {
    const float* x  = (const float*)d_in[0];
    const float* W0 = (const float*)d_in[1];
    const float* W1 = (const float*)d_in[2];
    const int*   ei = (const int*)d_in[3];

    const int N = in_sizes[0] / F_IN;       // 100000
    const int E = in_sizes[3] / 2;          // 3200000
    const int* src = ei;
    const int* dst = ei + E;

    const int NB = (N + BS - 1) / BS;       // 782
    const int C  = (E + CHE - 1) / CHE;     // 391
    const int SEGLEN = (C + NSEG - 1) / NSEG;  // 49
    const int NBG = (NB + 255) / 256;       // 4

    // workspace (all buffers 256B-aligned; ~25 MB):
    // H[C*NB] | S[8*NB] | SB[8*NB] | base[NB+1] | packed[E] | rowptr[N+1] | dinv[N] | g[N*16] | g2[N*8]
    size_t off = 0;
    int* H       = (int*)d_ws + off;           off += align64((size_t)C * NB);
    int* S       = (int*)d_ws + off;           off += align64((size_t)NSEG * NB);
    int* SB      = (int*)d_ws + off;           off += align64((size_t)NSEG * NB);
    int* base    = (int*)d_ws + off;           off += align64((size_t)NB + 1);
    int* packed  = (int*)d_ws + off;           off += align64((size_t)E);
    int* rowptr  = (int*)d_ws + off;           off += align64((size_t)N + 1);
    float* dinv  = (float*)d_ws + off;         off += align64((size_t)N);
    float* g     = (float*)d_ws + off;         off += align64((size_t)N * CH);
    float* g2    = (float*)d_ws + off;         off += align64((size_t)N * 8);

    float* out = (float*)d_out;

    // 1) per-chunk bucket histograms
    k_hist<<<C, 1024, 0, stream>>>(dst, E, NB, H);

    // 2) bucket bases: segmented column scan
    k_colsum8<<<dim3(NBG, NSEG), 256, 0, stream>>>(H, NB, C, SEGLEN, S);
    k_scanbase<<<1, 1024, 0, stream>>>(S, NB, E, base);
    k_segoff<<<NBG, 256, 0, stream>>>(S, base, NB, SB);
    k_colscan8<<<dim3(NBG, NSEG), 256, 0, stream>>>(H, SB, NB, C, SEGLEN);

    // 3) chunked counting-sort scatter into 128-node buckets
    k_scatter2<<<C, 1024, 0, stream>>>(src, dst, E, NB, H, packed);

    // 4) in-place per-bucket node sort -> CSR rowptr + dinv (replaces k_dinv)
    k_nodesort<<<NB, 256, 0, stream>>>(packed, base, N, rowptr, dinv);

    // 5) g = (x@W0) * dinv   [N][16]
    k_gemm1<<<2048, 256, 0, stream>>>(x, W0, dinv, g, N);

    // 6) layer1: CSR pull + register accumulation + fused relu/W1/dinv -> g2
    //    (replaces k_edge1 162us + k_layer2t + memset; zero atomics)
    k_agg1n<<<NB, 256, 0, stream>>>(g, packed, base, rowptr, W1, g2, N);

    // 7) layer2: CSR pull + register accumulation + fused exp epilogue
    k_agg2n<<<NB, 256, 0, stream>>>(g2, packed, base, rowptr, out, N);
}

// Round 13
// 381.240 us; speedup vs baseline: 1.8837x; 1.0677x over previous
//
#include <hip/hip_runtime.h>
#include <math.h>

#define F_IN 256
#define CH   16
#define NL   7

#define BS    128         // nodes per bucket (dL fits 7 bits, pack at bit 17)
#define CHE   8192        // edges per scatter chunk
#define MAXNB 1024        // LDS cap for bucket arrays (NB=782 actual)
#define NSEG  8           // segments for the column scan
#define ECAP  5120        // LDS edge-stage capacity per bucket (mean 4096, sd 64)

// ---------------------------------------------------------------- chunk histogram: H[c][b] = #edges of chunk c with dst in bucket b
__global__ __launch_bounds__(1024) void k_hist(const int* __restrict__ dst, int E, int NB,
                                               int* __restrict__ H) {
    __shared__ int h[MAXNB];
    int c = blockIdx.x, tid = threadIdx.x;
    for (int i = tid; i < NB; i += 1024) h[i] = 0;
    __syncthreads();
    int beg = c * CHE, end = min(beg + CHE, E);
    for (int e = beg + tid; e < end; e += 1024) atomicAdd(&h[dst[e] >> 7], 1);
    __syncthreads();
    int* Hrow = H + (size_t)c * NB;
    for (int i = tid; i < NB; i += 1024) Hrow[i] = h[i];
}

// ---------------------------------------------------------------- segmented column sums: S[s][b] = sum_{c in seg s} H[c][b]
__global__ __launch_bounds__(256) void k_colsum8(const int* __restrict__ H, int NB, int C,
                                                 int seglen, int* __restrict__ S) {
    int b = blockIdx.x * 256 + threadIdx.x;
    int s = blockIdx.y;
    if (b >= NB) return;
    int c0 = s * seglen, c1 = min(c0 + seglen, C);
    int acc = 0;
    for (int c = c0; c < c1; ++c) acc += H[(size_t)c * NB + b];
    S[(size_t)s * NB + b] = acc;
}

// ---------------------------------------------------------------- exclusive scan of bucket totals (1 WG, 2/thread; sums S inline)
__global__ __launch_bounds__(1024) void k_scanbase(const int* __restrict__ S, int NB, int E,
                                                   int* __restrict__ base) {
    __shared__ int sm[1024];
    int t = threadIdx.x;
    int i0 = 2 * t, i1 = 2 * t + 1;
    int v0 = 0, v1 = 0;
    if (i0 < NB) {
#pragma unroll
        for (int s = 0; s < NSEG; ++s) v0 += S[(size_t)s * NB + i0];
    }
    if (i1 < NB) {
#pragma unroll
        for (int s = 0; s < NSEG; ++s) v1 += S[(size_t)s * NB + i1];
    }
    sm[t] = v0 + v1;
    __syncthreads();
    for (int off = 1; off < 1024; off <<= 1) {
        int u = (t >= off) ? sm[t - off] : 0;
        __syncthreads();
        sm[t] += u;
        __syncthreads();
    }
    int ex = sm[t] - (v0 + v1);
    if (i0 < NB) base[i0] = ex;
    if (i1 < NB) base[i1] = ex + v0;
    if (t == 0) base[NB] = E;
}

// ---------------------------------------------------------------- per-segment start: SB[s][b] = base[b] + sum_{s'<s} S[s'][b]
__global__ __launch_bounds__(256) void k_segoff(const int* __restrict__ S, const int* __restrict__ base,
                                                int NB, int* __restrict__ SB) {
    int b = blockIdx.x * 256 + threadIdx.x;
    if (b >= NB) return;
    int run = base[b];
#pragma unroll
    for (int s = 0; s < NSEG; ++s) {
        SB[(size_t)s * NB + b] = run;
        run += S[(size_t)s * NB + b];
    }
}

// ---------------------------------------------------------------- segmented column scan: H[c][b] <- absolute start offset
__global__ __launch_bounds__(256) void k_colscan8(int* __restrict__ H, const int* __restrict__ SB,
                                                  int NB, int C, int seglen) {
    int b = blockIdx.x * 256 + threadIdx.x;
    int s = blockIdx.y;
    if (b >= NB) return;
    int c0 = s * seglen, c1 = min(c0 + seglen, C);
    int run = SB[(size_t)s * NB + b];
    for (int c = c0; c < c1; ++c) {
        size_t idx = (size_t)c * NB + b;
        int t = H[idx];
        H[idx] = run;
        run += t;
    }
}

// ---------------------------------------------------------------- scatter: LDS-local counting sort per chunk, linear writeout
__global__ __launch_bounds__(1024) void k_scatter2(const int* __restrict__ src, const int* __restrict__ dst,
                                                   int E, int NB, const int* __restrict__ H,
                                                   int* __restrict__ packed) {
    __shared__ int lcur[MAXNB];            // exclusive starts, then running cursors
    __shared__ int ldel[MAXNB];            // global base - local start
    __shared__ int ssc[1024];
    __shared__ int lval[CHE];
    __shared__ unsigned short lbkt[CHE];   // bucket id per local slot
    int c = blockIdx.x, tid = threadIdx.x;
    int beg = c * CHE, end = min(beg + CHE, E), n = end - beg;

    for (int i = tid; i < NB; i += 1024) lcur[i] = 0;
    __syncthreads();
    for (int e = beg + tid; e < end; e += 1024) atomicAdd(&lcur[dst[e] >> 7], 1);
    __syncthreads();

    // exclusive scan of lcur[0..NB), 2 elements per thread
    int i0 = 2 * tid;
    int a0 = (i0 < NB) ? lcur[i0] : 0;
    int a1 = (i0 + 1 < NB) ? lcur[i0 + 1] : 0;
    int tsum = a0 + a1;
    ssc[tid] = tsum;
    __syncthreads();
    for (int off = 1; off < 1024; off <<= 1) {
        int u = (tid >= off) ? ssc[tid - off] : 0;
        __syncthreads();
        ssc[tid] += u;
        __syncthreads();
    }
    int ex = ssc[tid] - tsum;
    if (i0 < NB) lcur[i0] = ex;
    if (i0 + 1 < NB) lcur[i0 + 1] = ex + a0;
    __syncthreads();

    const int* Hrow = H + (size_t)c * NB;
    for (int i = tid; i < NB; i += 1024) ldel[i] = Hrow[i] - lcur[i];
    __syncthreads();

    // place edges into LDS in bucket-sorted local order
    for (int e = beg + tid; e < end; e += 1024) {
        int d = dst[e], s = src[e];
        int bb = d >> 7;
        int p = atomicAdd(&lcur[bb], 1);
        lval[p] = s | ((d & (BS - 1)) << 17);
        lbkt[p] = (unsigned short)bb;
    }
    __syncthreads();

    // linear writeout (coalesced within bucket runs)
    for (int p = tid; p < n; p += 1024)
        packed[ldel[lbkt[p]] + p] = lval[p];
}

// ---------------------------------------------------------------- nodesort: in-place sort of each bucket by node; emits rowptr + dinv
__global__ __launch_bounds__(256) void k_nodesort(int* __restrict__ packed,
                                                  const int* __restrict__ base,
                                                  int N,
                                                  int* __restrict__ rowptr,
                                                  float* __restrict__ dinv) {
    __shared__ int ebuf[ECAP];
    __shared__ int cnt[BS], cur[BS];
    int b = blockIdx.x, tid = threadIdx.x;
    int beg = base[b], end = base[b + 1];
    int m = end - beg;
    int mc = min(m, ECAP);
    for (int i = tid; i < mc; i += 256) ebuf[i] = packed[beg + i];
    int vov = -1;                         // overflow edge (read BEFORE any in-place writes)
    int i2 = ECAP + tid;
    if (i2 < m) vov = packed[beg + i2];
    if (tid < BS) cnt[tid] = 0;
    __syncthreads();
    for (int i = tid; i < mc; i += 256) atomicAdd(&cnt[(ebuf[i] >> 17) & (BS - 1)], 1);
    if (vov >= 0) atomicAdd(&cnt[(vov >> 17) & (BS - 1)], 1);
    __syncthreads();
    int v = (tid < BS) ? cnt[tid] : 0;
    for (int off = 1; off < BS; off <<= 1) {
        int u = (tid < BS && tid >= off) ? cnt[tid - off] : 0;
        __syncthreads();
        if (tid < BS) cnt[tid] += u;
        __syncthreads();
    }
    if (tid < BS) {
        int ex = cnt[tid] - v;           // exclusive start
        cur[tid] = ex;
        int node = b * BS + tid;
        if (node < N) dinv[node] = rsqrtf((float)(v + 1));
        if (node <= N) rowptr[node] = beg + ex;
    }
    __syncthreads();
    for (int i = tid; i < mc; i += 256) {
        int vv = ebuf[i];
        int p = atomicAdd(&cur[(vv >> 17) & (BS - 1)], 1);
        packed[beg + p] = vv;
    }
    if (vov >= 0) {
        int p = atomicAdd(&cur[(vov >> 17) & (BS - 1)], 1);
        packed[beg + p] = vov;
    }
}

// ---------------------------------------------------------------- gemm1: g = (x @ W0) * dinv
// __launch_bounds__(256,4): allow ~128 VGPR so w[64] stays register-resident
// (R12: VGPR_Count=48 < 64 needed -> w spilled to scratch -> 156us).
// Two rows per iteration: 2 independent FMA chains, 32 lines in flight.
__global__ __launch_bounds__(256, 4) void k_gemm1(const float* __restrict__ x,
                                                  const float* __restrict__ W0,
                                                  const float* __restrict__ dinv,
                                                  float* __restrict__ g, int N) {
    int lane = threadIdx.x & 63;
    int q = lane >> 4;   // k-quarter (64 k's)
    int c = lane & 15;   // output channel
    float w[64];
#pragma unroll
    for (int t = 0; t < 64; ++t) w[t] = W0[(q * 64 + t) * CH + c];

    int wave  = (blockIdx.x * blockDim.x + threadIdx.x) >> 6;
    int nwave = (gridDim.x * blockDim.x) >> 6;

    int row = wave * 2;
    int stride = nwave * 2;
    for (; row + 1 < N; row += stride) {
        const float4* xp0 = (const float4*)(x + (size_t)row * F_IN + q * 64);
        const float4* xp1 = (const float4*)(x + (size_t)(row + 1) * F_IN + q * 64);
        float acc0 = 0.f, acc1 = 0.f;
#pragma unroll
        for (int t = 0; t < 16; ++t) {
            float4 v0 = xp0[t];
            float4 v1 = xp1[t];
            acc0 += v0.x * w[4*t] + v0.y * w[4*t+1] + v0.z * w[4*t+2] + v0.w * w[4*t+3];
            acc1 += v1.x * w[4*t] + v1.y * w[4*t+1] + v1.z * w[4*t+2] + v1.w * w[4*t+3];
        }
        acc0 += __shfl_xor(acc0, 16);
        acc0 += __shfl_xor(acc0, 32);
        acc1 += __shfl_xor(acc1, 16);
        acc1 += __shfl_xor(acc1, 32);
        if (q == 0) {
            g[(size_t)row * CH + c]       = acc0 * dinv[row];
            g[(size_t)(row + 1) * CH + c] = acc1 * dinv[row + 1];
        }
    }
    // tail (only if N odd)
    if (row < N) {
        const float4* xp0 = (const float4*)(x + (size_t)row * F_IN + q * 64);
        float acc0 = 0.f;
#pragma unroll
        for (int t = 0; t < 16; ++t) {
            float4 v0 = xp0[t];
            acc0 += v0.x * w[4*t] + v0.y * w[4*t+1] + v0.z * w[4*t+2] + v0.w * w[4*t+3];
        }
        acc0 += __shfl_xor(acc0, 16);
        acc0 += __shfl_xor(acc0, 32);
        if (q == 0) g[(size_t)row * CH + c] = acc0 * dinv[row];
    }
}

// ---------------------------------------------------------------- agg1n: layer1 CSR pull, REGISTER accumulation, fused relu+W1+dinv
// 2 threads per node (h = channel-half); zero atomics
__global__ __launch_bounds__(256) void k_agg1n(const float* __restrict__ g,
                                               const int* __restrict__ packed,
                                               const int* __restrict__ base,
                                               const int* __restrict__ rowptr,
                                               const float* __restrict__ W1,
                                               float* __restrict__ g2, int N) {
    __shared__ int ebuf[ECAP];
    __shared__ float hbuf[BS * 16];      // 8 KB
    __shared__ float w1s[16 * 8];        // W1 padded to stride 8
    int b = blockIdx.x, tid = threadIdx.x;
    int beg = base[b], end = base[b + 1], m = end - beg;
    int mc = min(m, ECAP);
    for (int i = tid; i < mc; i += 256) ebuf[i] = packed[beg + i];
    if (tid < 128) { int c = tid >> 3, j = tid & 7; w1s[tid] = (j < NL) ? W1[c * NL + j] : 0.f; }
    __syncthreads();

    int nL = tid >> 1, h = tid & 1;
    int n = b * BS + nL;
    float dv = 0.f;
    if (n < N) {
        int r0 = rowptr[n] - beg, r1 = rowptr[n + 1] - beg;
        dv = rsqrtf((float)(r1 - r0 + 1));
        const float4* gp = (const float4*)(g + (size_t)n * 16);
        float4 aL = gp[2 * h], aH = gp[2 * h + 1];   // self term
        int eEnd = min(r1, mc);
        int e = r0;
        for (; e + 4 <= eEnd; e += 4) {
            int s0 = ebuf[e] & 0x1FFFF, s1 = ebuf[e+1] & 0x1FFFF;
            int s2 = ebuf[e+2] & 0x1FFFF, s3 = ebuf[e+3] & 0x1FFFF;
            const float4* p0 = (const float4*)(g + (size_t)s0 * 16);
            const float4* p1 = (const float4*)(g + (size_t)s1 * 16);
            const float4* p2 = (const float4*)(g + (size_t)s2 * 16);
            const float4* p3 = (const float4*)(g + (size_t)s3 * 16);
            float4 l0 = p0[2*h], h0 = p0[2*h+1], l1 = p1[2*h], h1 = p1[2*h+1];
            float4 l2 = p2[2*h], h2 = p2[2*h+1], l3 = p3[2*h], h3 = p3[2*h+1];
            aL.x += l0.x + l1.x + l2.x + l3.x; aL.y += l0.y + l1.y + l2.y + l3.y;
            aL.z += l0.z + l1.z + l2.z + l3.z; aL.w += l0.w + l1.w + l2.w + l3.w;
            aH.x += h0.x + h1.x + h2.x + h3.x; aH.y += h0.y + h1.y + h2.y + h3.y;
            aH.z += h0.z + h1.z + h2.z + h3.z; aH.w += h0.w + h1.w + h2.w + h3.w;
        }
        for (; e < eEnd; ++e) {
            int s = ebuf[e] & 0x1FFFF;
            const float4* p = (const float4*)(g + (size_t)s * 16);
            float4 l = p[2*h], hh = p[2*h+1];
            aL.x += l.x; aL.y += l.y; aL.z += l.z; aL.w += l.w;
            aH.x += hh.x; aH.y += hh.y; aH.z += hh.z; aH.w += hh.w;
        }
        for (int e2 = max(r0, mc); e2 < r1; ++e2) {        // rare overflow tail
            int s = packed[beg + e2] & 0x1FFFF;
            const float4* p = (const float4*)(g + (size_t)s * 16);
            float4 l = p[2*h], hh = p[2*h+1];
            aL.x += l.x; aL.y += l.y; aL.z += l.z; aL.w += l.w;
            aH.x += hh.x; aH.y += hh.y; aH.z += hh.z; aH.w += hh.w;
        }
        float* hb = hbuf + nL * 16 + 8 * h;
        hb[0] = fmaxf(aL.x * dv, 0.f); hb[1] = fmaxf(aL.y * dv, 0.f);
        hb[2] = fmaxf(aL.z * dv, 0.f); hb[3] = fmaxf(aL.w * dv, 0.f);
        hb[4] = fmaxf(aH.x * dv, 0.f); hb[5] = fmaxf(aH.y * dv, 0.f);
        hb[6] = fmaxf(aH.z * dv, 0.f); hb[7] = fmaxf(aH.w * dv, 0.f);
    }
    __syncthreads();
    if (n < N) {
        int j0 = 4 * h;
        float y0 = 0.f, y1 = 0.f, y2 = 0.f, y3 = 0.f;
#pragma unroll
        for (int c = 0; c < 16; ++c) {
            float hc = hbuf[nL * 16 + c];
            y0 += hc * w1s[c * 8 + j0 + 0];
            y1 += hc * w1s[c * 8 + j0 + 1];
            y2 += hc * w1s[c * 8 + j0 + 2];
            y3 += hc * w1s[c * 8 + j0 + 3];   // j=7 column is zero-padded
        }
        float4 o; o.x = y0 * dv; o.y = y1 * dv; o.z = y2 * dv; o.w = y3 * dv;
        ((float4*)(g2 + (size_t)n * 8))[h] = o;
    }
}

// ---------------------------------------------------------------- agg2n: layer2 CSR pull, REGISTER accumulation, fused exp epilogue
__global__ __launch_bounds__(256) void k_agg2n(const float* __restrict__ g2,
                                               const int* __restrict__ packed,
                                               const int* __restrict__ base,
                                               const int* __restrict__ rowptr,
                                               float* __restrict__ out, int N) {
    __shared__ int ebuf[ECAP];
    int b = blockIdx.x, tid = threadIdx.x;
    int beg = base[b], end = base[b + 1], m = end - beg;
    int mc = min(m, ECAP);
    for (int i = tid; i < mc; i += 256) ebuf[i] = packed[beg + i];
    __syncthreads();

    int nL = tid >> 1, h = tid & 1;
    int n = b * BS + nL;
    if (n >= N) return;
    int r0 = rowptr[n] - beg, r1 = rowptr[n + 1] - beg;
    float dv = rsqrtf((float)(r1 - r0 + 1));
    float4 acc = ((const float4*)(g2 + (size_t)n * 8))[h];  // self term
    int eEnd = min(r1, mc);
    int e = r0;
    for (; e + 8 <= eEnd; e += 8) {
        int s[8];
#pragma unroll
        for (int k = 0; k < 8; ++k) s[k] = ebuf[e + k] & 0x1FFFF;
        float4 a[8];
#pragma unroll
        for (int k = 0; k < 8; ++k) a[k] = ((const float4*)(g2 + (size_t)s[k] * 8))[h];
#pragma unroll
        for (int k = 0; k < 8; ++k) {
            acc.x += a[k].x; acc.y += a[k].y; acc.z += a[k].z; acc.w += a[k].w;
        }
    }
    for (; e < eEnd; ++e) {
        int s = ebuf[e] & 0x1FFFF;
        float4 a = ((const float4*)(g2 + (size_t)s * 8))[h];
        acc.x += a.x; acc.y += a.y; acc.z += a.z; acc.w += a.w;
    }
    for (int e2 = max(r0, mc); e2 < r1; ++e2) {             // rare overflow tail
        int s = packed[beg + e2] & 0x1FFFF;
        float4 a = ((const float4*)(g2 + (size_t)s * 8))[h];
        acc.x += a.x; acc.y += a.y; acc.z += a.z; acc.w += a.w;
    }
    int j0 = 4 * h;
    float vals[4] = {acc.x, acc.y, acc.z, acc.w};
#pragma unroll
    for (int k = 0; k < 4; ++k)
        if (j0 + k < NL)
            out[(size_t)n * NL + j0 + k] = __expf(dv * vals[k]) + 1.0f;
}

static inline size_t align64(size_t n) { return (n + 63) & ~(size_t)63; }  // 64 elems = 256 B

extern "C" void kernel_launch(void* const* d_in, const int* in_sizes, int n_in,
                              void* d_out, int out_size, void* d_ws, size_t ws_size,
                              hipStream_t stream) {
    const float* x  = (const float*)d_in[0];
    const float* W0 = (const float*)d_in[1];
    const float* W1 = (const float*)d_in[2];
    const int*   ei = (const int*)d_in[3];

    const int N = in_sizes[0] / F_IN;       // 100000
    const int E = in_sizes[3] / 2;          // 3200000
    const int* src = ei;
    const int* dst = ei + E;

    const int NB = (N + BS - 1) / BS;       // 782
    const int C  = (E + CHE - 1) / CHE;     // 391
    const int SEGLEN = (C + NSEG - 1) / NSEG;  // 49
    const int NBG = (NB + 255) / 256;       // 4

    // workspace (all buffers 256B-aligned; ~25 MB):
    // H[C*NB] | S[8*NB] | SB[8*NB] | base[NB+1] | packed[E] | rowptr[N+1] | dinv[N] | g[N*16] | g2[N*8]
    size_t off = 0;
    int* H       = (int*)d_ws + off;           off += align64((size_t)C * NB);
    int* S       = (int*)d_ws + off;           off += align64((size_t)NSEG * NB);
    int* SB      = (int*)d_ws + off;           off += align64((size_t)NSEG * NB);
    int* base    = (int*)d_ws + off;           off += align64((size_t)NB + 1);
    int* packed  = (int*)d_ws + off;           off += align64((size_t)E);
    int* rowptr  = (int*)d_ws + off;           off += align64((size_t)N + 1);
    float* dinv  = (float*)d_ws + off;         off += align64((size_t)N);
    float* g     = (float*)d_ws + off;         off += align64((size_t)N * CH);
    float* g2    = (float*)d_ws + off;         off += align64((size_t)N * 8);

    float* out = (float*)d_out;

    // 1) per-chunk bucket histograms
    k_hist<<<C, 1024, 0, stream>>>(dst, E, NB, H);

    // 2) bucket bases: segmented column scan
    k_colsum8<<<dim3(NBG, NSEG), 256, 0, stream>>>(H, NB, C, SEGLEN, S);
    k_scanbase<<<1, 1024, 0, stream>>>(S, NB, E, base);
    k_segoff<<<NBG, 256, 0, stream>>>(S, base, NB, SB);
    k_colscan8<<<dim3(NBG, NSEG), 256, 0, stream>>>(H, SB, NB, C, SEGLEN);

    // 3) chunked counting-sort scatter into 128-node buckets
    k_scatter2<<<C, 1024, 0, stream>>>(src, dst, E, NB, H, packed);

    // 4) in-place per-bucket node sort -> CSR rowptr + dinv
    k_nodesort<<<NB, 256, 0, stream>>>(packed, base, N, rowptr, dinv);

    // 5) g = (x@W0) * dinv   [N][16]  (spill-free, 2 rows/iter)
    k_gemm1<<<2048, 256, 0, stream>>>(x, W0, dinv, g, N);

    // 6) layer1: CSR pull + register accumulation + fused relu/W1/dinv -> g2
    k_agg1n<<<NB, 256, 0, stream>>>(g, packed, base, rowptr, W1, g2, N);

    // 7) layer2: CSR pull + register accumulation + fused exp epilogue
    k_agg2n<<<NB, 256, 0, stream>>>(g2, packed, base, rowptr, out, N);
}